// Round 6
// baseline (61.052 us; speedup 1.0000x reference)
//
#include <hip/hip_runtime.h>
#include <math.h>

#define Bb 8
#define Nn 2048
#define Ff 64
#define ALPHA 0.2f
#define LN_EPS 1e-5f

typedef __attribute__((ext_vector_type(8))) short short8;
typedef __attribute__((ext_vector_type(4))) float f32x4;

__device__ inline unsigned short f2bf(float f) {
    unsigned u = __builtin_bit_cast(unsigned, f);
    u += 0x7fffu + ((u >> 16) & 1u);   // round-to-nearest-even
    return (unsigned short)(u >> 16);
}

// ------ Kernel A: pack adj into TRANSPOSED bitmask bitsT[i>>4][w][i&15] ------
__global__ __launch_bounds__(256) void pack_mask(const int* __restrict__ adj,
                                                 unsigned int* __restrict__ bitsT) {
    int g = blockIdx.x * blockDim.x + threadIdx.x;
    int lane = threadIdx.x & 63;
    int pred = adj[g] > 0;
    unsigned long long b = __ballot(pred);
    if ((lane & 31) == 0) {
        unsigned w32 = (unsigned)(b >> (lane & 32));
        int i = g >> 11, w = (g >> 5) & 63;
        bitsT[((size_t)(i >> 4) * 64 + w) * 16 + (i & 15)] = w32;
    }
}

// -- Kernel B: x-scale, h=x@W, LayerNorm, s1/s2, h fp32 + FRAGMENT-TILED hT2 --
// 8 nodes/block, 4 waves, 2 nodes/wave. Grid 2048.
__global__ __launch_bounds__(256) void node_transform(
    const float* __restrict__ in, const float* __restrict__ W,
    const float* __restrict__ a, const float* __restrict__ nw,
    const float* __restrict__ nb, const float* __restrict__ gam,
    const float* __restrict__ bet,
    float* __restrict__ h, float* __restrict__ s1, float* __restrict__ s2,
    unsigned short* __restrict__ hT2)
{
    __shared__ float Wl[64 * 64];
    __shared__ unsigned short h_bf[8][72];
    int t = threadIdx.x;
#pragma unroll
    for (int s = 0; s < 4; ++s)
        ((float4*)Wl)[t + 256 * s] = ((const float4*)W)[t + 256 * s];
    __syncthreads();
    int wave = t >> 6, lane = t & 63;
    float ga = gam[lane], be = bet[lane];
    float a1 = a[lane], a2 = a[64 + lane];
    int node0 = blockIdx.x * 8;
#pragma unroll
    for (int nn = 0; nn < 2; ++nn) {
        int nl = wave * 2 + nn;
        int node = node0 + nl;
        int n = node & (Nn - 1);
        float xv = in[node * 64 + lane] * (nw[n] + 1.0f) + nb[n];
        float hv0 = 0.f, hv1 = 0.f, hv2 = 0.f, hv3 = 0.f;
#pragma unroll
        for (int k4 = 0; k4 < 16; ++k4) {
            hv0 = fmaf(__shfl(xv, k4 * 4 + 0, 64), Wl[(k4 * 4 + 0) * 64 + lane], hv0);
            hv1 = fmaf(__shfl(xv, k4 * 4 + 1, 64), Wl[(k4 * 4 + 1) * 64 + lane], hv1);
            hv2 = fmaf(__shfl(xv, k4 * 4 + 2, 64), Wl[(k4 * 4 + 2) * 64 + lane], hv2);
            hv3 = fmaf(__shfl(xv, k4 * 4 + 3, 64), Wl[(k4 * 4 + 3) * 64 + lane], hv3);
        }
        float hv = (hv0 + hv1) + (hv2 + hv3);
        float mu = hv;
#pragma unroll
        for (int o = 32; o; o >>= 1) mu += __shfl_xor(mu, o, 64);
        mu *= (1.f / 64.f);
        float d = hv - mu;
        float var = d * d;
#pragma unroll
        for (int o = 32; o; o >>= 1) var += __shfl_xor(var, o, 64);
        var *= (1.f / 64.f);
        float hn = d * rsqrtf(var + LN_EPS) * ga + be;
        h[node * 64 + lane] = hn;
        h_bf[nl][lane] = f2bf(hn);
        float p1 = hn * a1, p2 = hn * a2;
#pragma unroll
        for (int o = 32; o; o >>= 1) {
            p1 += __shfl_xor(p1, o, 64);
            p2 += __shfl_xor(p2, o, 64);
        }
        if (lane == 0) { s1[node] = p1; s2[node] = p2; }
    }
    __syncthreads();
    // fragment repack: block = 8 nodes = one (jw, ag2) e-run of 8.
    // 128 threads x 4 shorts (8B) cover 4 fb x 16 am x 8 e = 512 shorts.
    if (t < 128) {
        int b = node0 >> 11, j0 = node0 & (Nn - 1);
        int jw = j0 >> 5, ag2 = (j0 & 31) >> 3;
        int flat = t * 4, fb = flat >> 7, rem = flat & 127;
        int am2 = rem >> 3, e0 = rem & 7;           // e0 in {0,4}
        unsigned short v[4];
#pragma unroll
        for (int i = 0; i < 4; ++i) v[i] = h_bf[e0 + i][fb * 16 + am2];
        size_t dst = ((size_t)((b * 64 + jw) * 4 + fb)) * 512 + (ag2 * 16 + am2) * 8 + e0;
        *(uint2*)&hT2[dst] = *(uint2*)v;
    }
}

// ---- Kernel C: fused softmax + MFMA PV, full 1-step prefetch pipeline -------
// grid (128, 8): 16 rows/block, 256 thr = 4 waves, wave = jq (j-quarter).
__global__ __launch_bounds__(256) void attention5(
    const float* __restrict__ h, const unsigned short* __restrict__ hT2,
    const float* __restrict__ s1g, const float* __restrict__ s2g,
    const unsigned int* __restrict__ bitsT, float* __restrict__ out)
{
    __shared__ float paccl[4][16][68];   // [jq][row][f] padded
    __shared__ float zl[4][16];

    int t = threadIdx.x, jq = t >> 6, lane = t & 63;
    int am = lane & 15, ag = lane >> 4;
    int b = blockIdx.y;
    int i0 = blockIdx.x * 16;
    int row = i0 + am;

    float s1r = s1g[b * Nn + row];
    const unsigned int* btq = bitsT + ((size_t)blockIdx.x * 64 + jq * 16) * 16 + am;
    const float* s2q = s2g + b * Nn + jq * 512 + 8 * ag;
    const unsigned short* fqp = hT2 + ((size_t)(b * 64 + jq * 16) * 4) * 512 + lane * 8;

    f32x4 acc0 = {0,0,0,0}, acc1 = {0,0,0,0}, acc2 = {0,0,0,0}, acc3 = {0,0,0,0};
    float zp = 0.f;

    unsigned wdA, wdB;
    float4 saA, sbA, saB, sbB;
    short8 fA0, fA1, fA2, fA3, fB0, fB1, fB2, fB3;

#define ISSUE(W, wd_, sa_, sb_, f0_, f1_, f2_, f3_)                         \
        wd_ = btq[(W) * 16];                                                \
        sa_ = *(const float4*)&s2q[(W) * 32];                               \
        sb_ = *(const float4*)&s2q[(W) * 32 + 4];                           \
        f0_ = *(const short8*)&fqp[(size_t)(W) * 2048 + 0 * 512];           \
        f1_ = *(const short8*)&fqp[(size_t)(W) * 2048 + 1 * 512];           \
        f2_ = *(const short8*)&fqp[(size_t)(W) * 2048 + 2 * 512];           \
        f3_ = *(const short8*)&fqp[(size_t)(W) * 2048 + 3 * 512];

#define COMPUTE(wd_, sa_, sb_, f0_, f1_, f2_, f3_) do {                     \
        float se[8] = {sa_.x, sa_.y, sa_.z, sa_.w, sb_.x, sb_.y, sb_.z, sb_.w}; \
        short8 af;                                                          \
        _Pragma("unroll")                                                   \
        for (int e = 0; e < 8; ++e) {                                       \
            float x = s1r + se[e];                                          \
            float lr = fmaxf(x, ALPHA * x);                                 \
            float p = ((wd_ >> (8 * ag + e)) & 1u) ? __expf(lr) : 0.f;      \
            zp += p;                                                        \
            af[e] = (short)f2bf(p);                                         \
        }                                                                   \
        acc0 = __builtin_amdgcn_mfma_f32_16x16x32_bf16(af, f0_, acc0, 0,0,0);\
        acc1 = __builtin_amdgcn_mfma_f32_16x16x32_bf16(af, f1_, acc1, 0,0,0);\
        acc2 = __builtin_amdgcn_mfma_f32_16x16x32_bf16(af, f2_, acc2, 0,0,0);\
        acc3 = __builtin_amdgcn_mfma_f32_16x16x32_bf16(af, f3_, acc3, 0,0,0);\
    } while (0)

    ISSUE(0, wdA, saA, sbA, fA0, fA1, fA2, fA3);
#pragma unroll
    for (int w2 = 0; w2 < 8; ++w2) {
        ISSUE(2 * w2 + 1, wdB, saB, sbB, fB0, fB1, fB2, fB3);
        COMPUTE(wdA, saA, sbA, fA0, fA1, fA2, fA3);
        if (w2 < 7) {
            ISSUE(2 * w2 + 2, wdA, saA, sbA, fA0, fA1, fA2, fA3);
        }
        COMPUTE(wdB, saB, sbB, fB0, fB1, fB2, fB3);
    }
#undef ISSUE
#undef COMPUTE

    // Z partial for row am over this jq
    zp += __shfl_xor(zp, 16, 64);
    zp += __shfl_xor(zp, 32, 64);
    if (lane < 16) zl[jq][am] = zp;

    // acc tiles -> LDS
#pragma unroll
    for (int q = 0; q < 4; ++q) {
        paccl[jq][ag * 4 + q][0 * 16 + am] = acc0[q];
        paccl[jq][ag * 4 + q][1 * 16 + am] = acc1[q];
        paccl[jq][ag * 4 + q][2 * 16 + am] = acc2[q];
        paccl[jq][ag * 4 + q][3 * 16 + am] = acc3[q];
    }
    __syncthreads();

    // combine over jq + residual + elu. 256 thr = 16 rows x 16 fquads.
    int rl = t >> 4, fq2 = t & 15;
    float zs = zl[0][rl] + zl[1][rl] + zl[2][rl] + zl[3][rl];
    float sx = 0.f, sy = 0.f, sz = 0.f, sw = 0.f;
#pragma unroll
    for (int q4 = 0; q4 < 4; ++q4) {
        const float* p = &paccl[q4][rl][fq2 * 4];
        sx += p[0]; sy += p[1]; sz += p[2]; sw += p[3];
    }
    float zinv = 1.f / zs;
    int gi = i0 + rl;
    size_t base = ((size_t)(b * Nn + gi)) * 64 + fq2 * 4;
    float4 hv = *(const float4*)&h[base];
    float4 o;
    o.x = sx * zinv + hv.x; o.x = o.x > 0.f ? o.x : expm1f(o.x);
    o.y = sy * zinv + hv.y; o.y = o.y > 0.f ? o.y : expm1f(o.y);
    o.z = sz * zinv + hv.z; o.z = o.z > 0.f ? o.z : expm1f(o.z);
    o.w = sw * zinv + hv.w; o.w = o.w > 0.f ? o.w : expm1f(o.w);
    *(float4*)&out[base] = o;
}

// ---------------- launch ----------------
extern "C" void kernel_launch(void* const* d_in, const int* in_sizes, int n_in,
                              void* d_out, int out_size, void* d_ws, size_t ws_size,
                              hipStream_t stream) {
    const float* in  = (const float*)d_in[0];
    const int*   adj = (const int*)d_in[1];
    const float* W   = (const float*)d_in[2];
    const float* a   = (const float*)d_in[3];
    const float* nw  = (const float*)d_in[4];
    const float* nb  = (const float*)d_in[5];
    const float* gam = (const float*)d_in[6];
    const float* bet = (const float*)d_in[7];
    float* out = (float*)d_out;

    char* ws = (char*)d_ws;
    float* h  = (float*)ws;                                      // 4 MB
    float* s1 = (float*)(ws + (size_t)Bb * Nn * Ff * 4);         // 64 KB
    float* s2 = s1 + (size_t)Bb * Nn;                            // 64 KB
    unsigned int* bitsT = (unsigned int*)(s2 + (size_t)Bb * Nn); // 512 KB
    unsigned short* hT2 = (unsigned short*)(bitsT + (size_t)Nn * Nn / 32); // 2 MB

    hipLaunchKernelGGL(pack_mask, dim3(Nn * Nn / 256), dim3(256), 0, stream, adj, bitsT);
    hipLaunchKernelGGL(node_transform, dim3(Bb * Nn / 8), dim3(256), 0, stream,
                       in, W, a, nw, nb, gam, bet, h, s1, s2, hT2);
    hipLaunchKernelGGL(attention5, dim3(Nn / 16, Bb), dim3(256), 0, stream,
                       h, hT2, s1, s2, bitsT, out);
}

// Round 7
// 56.983 us; speedup vs baseline: 1.0714x; 1.0714x over previous
//
#include <hip/hip_runtime.h>
#include <math.h>

#define Bb 8
#define Nn 2048
#define ALPHA 0.2f
#define LN_EPS 1e-5f
#define LOG2E 1.4426950408889634f

typedef __attribute__((ext_vector_type(8))) short short8;
typedef __attribute__((ext_vector_type(4))) float f32x4;
typedef __attribute__((ext_vector_type(4))) int int4v;

__device__ inline unsigned short f2bf(float f) {
    unsigned u = __builtin_bit_cast(unsigned, f);
    u += 0x7fffu + ((u >> 16) & 1u);   // RNE
    return (unsigned short)(u >> 16);
}

__device__ __forceinline__ void gll16(const void* g, void* l) {
    __builtin_amdgcn_global_load_lds(
        (const __attribute__((address_space(1))) unsigned int*)g,
        (__attribute__((address_space(3))) unsigned int*)l, 16, 0, 0);
}

// ------ Kernel A: pack adj into TRANSPOSED bitmask bitsT[i>>4][w][i&15] ------
__global__ __launch_bounds__(256) void pack_mask(const int* __restrict__ adj,
                                                 unsigned int* __restrict__ bitsT) {
    int g = blockIdx.x * blockDim.x + threadIdx.x;
    int lane = threadIdx.x & 63;
    int pred = adj[g] > 0;
    unsigned long long b = __ballot(pred);
    if ((lane & 31) == 0) {
        unsigned w32 = (unsigned)(b >> (lane & 32));
        int i = g >> 11, w = (g >> 5) & 63;
        bitsT[((size_t)(i >> 4) * 64 + w) * 16 + (i & 15)] = w32;
    }
}

// -- Kernel B: x-scale, h=x@W, LayerNorm, s1L/s2L (pre-scaled by log2e), hT2 --
__global__ __launch_bounds__(256) void node_transform(
    const float* __restrict__ in, const float* __restrict__ W,
    const float* __restrict__ a, const float* __restrict__ nw,
    const float* __restrict__ nb, const float* __restrict__ gam,
    const float* __restrict__ bet,
    float* __restrict__ h, float* __restrict__ s1L, float* __restrict__ s2L,
    unsigned short* __restrict__ hT2)
{
    __shared__ float Wl[64 * 64];
    __shared__ unsigned short h_bf[8][72];
    int t = threadIdx.x;
#pragma unroll
    for (int s = 0; s < 4; ++s)
        ((float4*)Wl)[t + 256 * s] = ((const float4*)W)[t + 256 * s];
    __syncthreads();
    int wave = t >> 6, lane = t & 63;
    float ga = gam[lane], be = bet[lane];
    float a1 = a[lane], a2 = a[64 + lane];
    int node0 = blockIdx.x * 8;
#pragma unroll
    for (int nn = 0; nn < 2; ++nn) {
        int nl = wave * 2 + nn;
        int node = node0 + nl;
        int n = node & (Nn - 1);
        float xv = in[node * 64 + lane] * (nw[n] + 1.0f) + nb[n];
        float hv0 = 0.f, hv1 = 0.f, hv2 = 0.f, hv3 = 0.f;
#pragma unroll
        for (int k4 = 0; k4 < 16; ++k4) {
            hv0 = fmaf(__shfl(xv, k4 * 4 + 0, 64), Wl[(k4 * 4 + 0) * 64 + lane], hv0);
            hv1 = fmaf(__shfl(xv, k4 * 4 + 1, 64), Wl[(k4 * 4 + 1) * 64 + lane], hv1);
            hv2 = fmaf(__shfl(xv, k4 * 4 + 2, 64), Wl[(k4 * 4 + 2) * 64 + lane], hv2);
            hv3 = fmaf(__shfl(xv, k4 * 4 + 3, 64), Wl[(k4 * 4 + 3) * 64 + lane], hv3);
        }
        float hv = (hv0 + hv1) + (hv2 + hv3);
        float mu = hv;
#pragma unroll
        for (int o = 32; o; o >>= 1) mu += __shfl_xor(mu, o, 64);
        mu *= (1.f / 64.f);
        float d = hv - mu;
        float var = d * d;
#pragma unroll
        for (int o = 32; o; o >>= 1) var += __shfl_xor(var, o, 64);
        var *= (1.f / 64.f);
        float hn = d * rsqrtf(var + LN_EPS) * ga + be;
        h[node * 64 + lane] = hn;
        h_bf[nl][lane] = f2bf(hn);
        float p1 = hn * a1, p2 = hn * a2;
#pragma unroll
        for (int o = 32; o; o >>= 1) {
            p1 += __shfl_xor(p1, o, 64);
            p2 += __shfl_xor(p2, o, 64);
        }
        if (lane == 0) { s1L[node] = p1 * LOG2E; s2L[node] = p2 * LOG2E; }
    }
    __syncthreads();
    // fragment repack: block = 8 nodes = one (jw, ag2) e-run of 8.
    if (t < 128) {
        int b = node0 >> 11, j0 = node0 & (Nn - 1);
        int jw = j0 >> 5, ag2 = (j0 & 31) >> 3;
        int flat = t * 4, fb = flat >> 7, rem = flat & 127;
        int am2 = rem >> 3, e0 = rem & 7;
        unsigned short v[4];
#pragma unroll
        for (int i = 0; i < 4; ++i) v[i] = h_bf[e0 + i][fb * 16 + am2];
        size_t dst = ((size_t)((b * 64 + jw) * 4 + fb)) * 512 + (ag2 * 16 + am2) * 8 + e0;
        *(uint2*)&hT2[dst] = *(uint2*)v;
    }
}

// ---- Kernel C: LDS-shared fragments, counted-vmcnt pipeline, MFMA PV -------
// grid (32, 2, 8): bx = 64-row tile, jh = j-half, b = batch. 256 thr = 4 waves.
// Wave wr owns rows [bx*64 + wr*16, +16); all waves share the j-word stream.
__global__ __launch_bounds__(256) void attention6(
    const unsigned short* __restrict__ hT2,
    const float* __restrict__ s1L, const float* __restrict__ s2L,
    const unsigned int* __restrict__ bitsT,
    float* __restrict__ pacc, float* __restrict__ pz)
{
    __shared__ unsigned short frag_lds[4][4][512];  // 16 KB ring of B-frag sets
    __shared__ float s2l[1024];                     // 4 KB
    __shared__ unsigned int mask_lds[2048];         // 8 KB

    int t = threadIdx.x, wr = t >> 6, lane = t & 63;
    int am = lane & 15, ag = lane >> 4;
    int bx = blockIdx.x, jh = blockIdx.y, b = blockIdx.z;

    // stage s2 (pre-scaled) and mask into LDS
    ((float4*)s2l)[t] = ((const float4*)(s2L + b * Nn + jh * 1024))[t];
#pragma unroll
    for (int s = 0; s < 2; ++s) {
        int idx = s * 256 + t;                       // 0..511 dword4-groups
        int wrc = idx >> 7;
        size_t srcoff = (size_t)(bx * 4 + wrc) * 1024 + jh * 512 + (idx & 127) * 4;
        *(uint4*)&mask_lds[idx * 4] = *(const uint4*)&bitsT[srcoff];
    }
    float s1r = s1L[b * Nn + bx * 64 + wr * 16 + am];
    __syncthreads();

    const unsigned short* slab = hT2 + ((size_t)(b * 64 + jh * 32) * 4) * 512;

    // prologue: stage words 0,1 (each wave stages its fb=wr slice, 1 KB)
    gll16(slab + (size_t)0 * 2048 + wr * 512 + lane * 8, &frag_lds[0][wr][0]);
    gll16(slab + (size_t)1 * 2048 + wr * 512 + lane * 8, &frag_lds[1][wr][0]);
    asm volatile("s_waitcnt vmcnt(1)" ::: "memory");
    __builtin_amdgcn_s_barrier();

    f32x4 acc0 = {0,0,0,0}, acc1 = {0,0,0,0}, acc2 = {0,0,0,0}, acc3 = {0,0,0,0};
    f32x4 accz = {0,0,0,0};
    const short8 vone = {(short)0x3F80, (short)0x3F80, (short)0x3F80, (short)0x3F80,
                         (short)0x3F80, (short)0x3F80, (short)0x3F80, (short)0x3F80};

#pragma unroll 4
    for (int W = 0; W < 32; ++W) {
        int buf = W & 3;
        unsigned wd = mask_lds[wr * 512 + W * 16 + am];
        float4 sa = *(const float4*)&s2l[W * 32 + 8 * ag];
        float4 sb = *(const float4*)&s2l[W * 32 + 8 * ag + 4];
        short8 f0 = *(const short8*)&frag_lds[buf][0][lane * 8];
        short8 f1 = *(const short8*)&frag_lds[buf][1][lane * 8];
        short8 f2 = *(const short8*)&frag_lds[buf][2][lane * 8];
        short8 f3 = *(const short8*)&frag_lds[buf][3][lane * 8];
        // stage W+2 (wrap keeps the vmcnt cadence uniform; overwrites a dead buf)
        int wn = (W + 2) & 31;
        gll16(slab + (size_t)wn * 2048 + wr * 512 + lane * 8,
              &frag_lds[(W + 2) & 3][wr][0]);
        // P for this wave's 16 rows x 32 j
        float se[8] = {sa.x, sa.y, sa.z, sa.w, sb.x, sb.y, sb.z, sb.w};
        float p[8];
#pragma unroll
        for (int e = 0; e < 8; ++e) {
            float x = s1r + se[e];
            float lr = fmaxf(x, ALPHA * x);
            float ev = __builtin_amdgcn_exp2f(lr);
            p[e] = ((wd >> (8 * ag + e)) & 1u) ? ev : 0.f;
        }
        int4v aw;
        aw.x = __builtin_amdgcn_perm(__builtin_bit_cast(unsigned, p[1]),
                                     __builtin_bit_cast(unsigned, p[0]), 0x07060302u);
        aw.y = __builtin_amdgcn_perm(__builtin_bit_cast(unsigned, p[3]),
                                     __builtin_bit_cast(unsigned, p[2]), 0x07060302u);
        aw.z = __builtin_amdgcn_perm(__builtin_bit_cast(unsigned, p[5]),
                                     __builtin_bit_cast(unsigned, p[4]), 0x07060302u);
        aw.w = __builtin_amdgcn_perm(__builtin_bit_cast(unsigned, p[7]),
                                     __builtin_bit_cast(unsigned, p[6]), 0x07060302u);
        short8 af = __builtin_bit_cast(short8, aw);
        acc0 = __builtin_amdgcn_mfma_f32_16x16x32_bf16(af, f0, acc0, 0, 0, 0);
        acc1 = __builtin_amdgcn_mfma_f32_16x16x32_bf16(af, f1, acc1, 0, 0, 0);
        acc2 = __builtin_amdgcn_mfma_f32_16x16x32_bf16(af, f2, acc2, 0, 0, 0);
        acc3 = __builtin_amdgcn_mfma_f32_16x16x32_bf16(af, f3, acc3, 0, 0, 0);
        accz = __builtin_amdgcn_mfma_f32_16x16x32_bf16(af, vone, accz, 0, 0, 0);
        asm volatile("s_waitcnt vmcnt(1)" ::: "memory");
        __builtin_amdgcn_s_barrier();
    }

    // write partials: rows ag*4+q, f = fb*16+am
    size_t pb = ((size_t)((b * 128 + bx * 4 + wr) * 2 + jh)) * 1024;
#pragma unroll
    for (int q = 0; q < 4; ++q) {
        int r = ag * 4 + q;
        pacc[pb + r * 64 +  0 + am] = acc0[q];
        pacc[pb + r * 64 + 16 + am] = acc1[q];
        pacc[pb + r * 64 + 32 + am] = acc2[q];
        pacc[pb + r * 64 + 48 + am] = acc3[q];
    }
    if (am == 0) {
        size_t zb = ((size_t)((b * 128 + bx * 4 + wr) * 2 + jh)) * 16;
#pragma unroll
        for (int q = 0; q < 4; ++q) pz[zb + ag * 4 + q] = accz[q];
    }
}

// ---- Kernel D: combine j-halves, normalize, residual, elu ------------------
// grid (128, 8), 256 thr: t -> row r=t>>4 (16 rows), fquad fq=t&15.
__global__ __launch_bounds__(256) void combine(
    const float* __restrict__ pacc, const float* __restrict__ pz,
    const float* __restrict__ h, float* __restrict__ out)
{
    int t = threadIdx.x, it = blockIdx.x, b = blockIdx.y;
    int r = t >> 4, fq = t & 15;
    size_t base0 = ((size_t)((b * 128 + it) * 2 + 0)) * 1024 + r * 64 + fq * 4;
    float4 a0 = *(const float4*)&pacc[base0];
    float4 a1 = *(const float4*)&pacc[base0 + 1024];
    float z = pz[((size_t)((b * 128 + it) * 2 + 0)) * 16 + r]
            + pz[((size_t)((b * 128 + it) * 2 + 1)) * 16 + r];
    float zinv = 1.f / z;
    size_t ob = ((size_t)(b * Nn + it * 16 + r)) * 64 + fq * 4;
    float4 hv = *(const float4*)&h[ob];
    float4 o;
    o.x = (a0.x + a1.x) * zinv + hv.x; o.x = o.x > 0.f ? o.x : expm1f(o.x);
    o.y = (a0.y + a1.y) * zinv + hv.y; o.y = o.y > 0.f ? o.y : expm1f(o.y);
    o.z = (a0.z + a1.z) * zinv + hv.z; o.z = o.z > 0.f ? o.z : expm1f(o.z);
    o.w = (a0.w + a1.w) * zinv + hv.w; o.w = o.w > 0.f ? o.w : expm1f(o.w);
    *(float4*)&out[ob] = o;
}

// ---------------- launch ----------------
extern "C" void kernel_launch(void* const* d_in, const int* in_sizes, int n_in,
                              void* d_out, int out_size, void* d_ws, size_t ws_size,
                              hipStream_t stream) {
    const float* in  = (const float*)d_in[0];
    const int*   adj = (const int*)d_in[1];
    const float* W   = (const float*)d_in[2];
    const float* a   = (const float*)d_in[3];
    const float* nw  = (const float*)d_in[4];
    const float* nb  = (const float*)d_in[5];
    const float* gam = (const float*)d_in[6];
    const float* bet = (const float*)d_in[7];
    float* out = (float*)d_out;

    char* ws = (char*)d_ws;
    float* h   = (float*)ws;                                       // 4 MB
    float* s1L = (float*)(ws + (size_t)Bb * Nn * 64 * 4);          // 64 KB
    float* s2L = s1L + (size_t)Bb * Nn;                            // 64 KB
    unsigned int* bitsT = (unsigned int*)(s2L + (size_t)Bb * Nn);  // 512 KB
    unsigned short* hT2 = (unsigned short*)(bitsT + (size_t)Nn * Nn / 32); // 2 MB
    float* pacc = (float*)(hT2 + (size_t)Bb * 64 * Nn);            // 8 MB
    float* pz   = pacc + (size_t)Bb * 128 * 2 * 1024;              // 128 KB

    hipLaunchKernelGGL(pack_mask, dim3(Nn * Nn / 256), dim3(256), 0, stream, adj, bitsT);
    hipLaunchKernelGGL(node_transform, dim3(Bb * Nn / 8), dim3(256), 0, stream,
                       in, W, a, nw, nb, gam, bet, h, s1L, s2L, hT2);
    hipLaunchKernelGGL(attention6, dim3(Nn / 64, 2, Bb), dim3(256), 0, stream,
                       hT2, s1L, s2L, bitsT, pacc, pz);
    hipLaunchKernelGGL(combine, dim3(Nn / 16, Bb), dim3(256), 0, stream,
                       pacc, pz, h, out);
}

// Round 8
// 54.457 us; speedup vs baseline: 1.1211x; 1.0464x over previous
//
#include <hip/hip_runtime.h>
#include <math.h>

#define Bb 8
#define Nn 2048
#define ALPHA 0.2f
#define LN_EPS 1e-5f
#define LOG2E 1.4426950408889634f

typedef __attribute__((ext_vector_type(8))) short short8;
typedef __attribute__((ext_vector_type(4))) float f32x4;
typedef __attribute__((ext_vector_type(4))) int int4v;

__device__ inline unsigned short f2bf(float f) {
    unsigned u = __builtin_bit_cast(unsigned, f);
    u += 0x7fffu + ((u >> 16) & 1u);   // RNE
    return (unsigned short)(u >> 16);
}

__device__ __forceinline__ void gll16(const void* g, void* l) {
    __builtin_amdgcn_global_load_lds(
        (const __attribute__((address_space(1))) unsigned int*)g,
        (__attribute__((address_space(3))) unsigned int*)l, 16, 0, 0);
}

// ------ Kernel A: pack adj into TRANSPOSED bitmask bitsT[i>>4][w][i&15] ------
__global__ __launch_bounds__(256) void pack_mask(const int* __restrict__ adj,
                                                 unsigned int* __restrict__ bitsT) {
    int g = blockIdx.x * blockDim.x + threadIdx.x;
    int lane = threadIdx.x & 63;
    int pred = adj[g] > 0;
    unsigned long long b = __ballot(pred);
    if ((lane & 31) == 0) {
        unsigned w32 = (unsigned)(b >> (lane & 32));
        int i = g >> 11, w = (g >> 5) & 63;
        bitsT[((size_t)(i >> 4) * 64 + w) * 16 + (i & 15)] = w32;
    }
}

// -- Kernel B: x-scale, h=x@W, LayerNorm, s1L/s2L (pre-scaled by log2e), hT2 --
// 4 nodes/block, 1 node/wave. Grid 4096.
__global__ __launch_bounds__(256) void node_transform(
    const float* __restrict__ in, const float* __restrict__ W,
    const float* __restrict__ a, const float* __restrict__ nw,
    const float* __restrict__ nb, const float* __restrict__ gam,
    const float* __restrict__ bet,
    float* __restrict__ h, float* __restrict__ s1L, float* __restrict__ s2L,
    unsigned short* __restrict__ hT2)
{
    __shared__ float Wl[64 * 64];
    __shared__ unsigned short h_bf[4][64];
    int t = threadIdx.x;
#pragma unroll
    for (int s = 0; s < 4; ++s)
        ((float4*)Wl)[t + 256 * s] = ((const float4*)W)[t + 256 * s];
    __syncthreads();
    int wv = t >> 6, lane = t & 63;
    int node = blockIdx.x * 4 + wv;
    int n = node & (Nn - 1);
    float xv = in[node * 64 + lane] * (nw[n] + 1.0f) + nb[n];
    float hv0 = 0.f, hv1 = 0.f, hv2 = 0.f, hv3 = 0.f;
#pragma unroll
    for (int k4 = 0; k4 < 16; ++k4) {
        hv0 = fmaf(__shfl(xv, k4 * 4 + 0, 64), Wl[(k4 * 4 + 0) * 64 + lane], hv0);
        hv1 = fmaf(__shfl(xv, k4 * 4 + 1, 64), Wl[(k4 * 4 + 1) * 64 + lane], hv1);
        hv2 = fmaf(__shfl(xv, k4 * 4 + 2, 64), Wl[(k4 * 4 + 2) * 64 + lane], hv2);
        hv3 = fmaf(__shfl(xv, k4 * 4 + 3, 64), Wl[(k4 * 4 + 3) * 64 + lane], hv3);
    }
    float hv = (hv0 + hv1) + (hv2 + hv3);
    float mu = hv;
#pragma unroll
    for (int o = 32; o; o >>= 1) mu += __shfl_xor(mu, o, 64);
    mu *= (1.f / 64.f);
    float d = hv - mu;
    float var = d * d;
#pragma unroll
    for (int o = 32; o; o >>= 1) var += __shfl_xor(var, o, 64);
    var *= (1.f / 64.f);
    float hn = d * rsqrtf(var + LN_EPS) * gam[lane] + bet[lane];
    h[node * 64 + lane] = hn;
    h_bf[wv][lane] = f2bf(hn);
    float p1 = hn * a[lane], p2 = hn * a[64 + lane];
#pragma unroll
    for (int o = 32; o; o >>= 1) {
        p1 += __shfl_xor(p1, o, 64);
        p2 += __shfl_xor(p2, o, 64);
    }
    if (lane == 0) { s1L[node] = p1 * LOG2E; s2L[node] = p2 * LOG2E; }
    __syncthreads();
    // fragment repack: block = 4 nodes = one e-run of 4 at (jw, ag2, e0).
    if (t < 64) {
        int fb = t >> 4, am2 = t & 15;
        int node0 = blockIdx.x * 4;
        int b = node0 >> 11, j0 = node0 & (Nn - 1);
        int jw = j0 >> 5, ag2 = (j0 & 31) >> 3, e0 = j0 & 7;
        unsigned short v[4];
#pragma unroll
        for (int i = 0; i < 4; ++i) v[i] = h_bf[i][fb * 16 + am2];
        size_t dst = ((size_t)((b * 64 + jw) * 4 + fb)) * 512 + (ag2 * 16 + am2) * 8 + e0;
        *(uint2*)&hT2[dst] = *(uint2*)v;
    }
}

// ---- Kernel C: whole-row fused attention. 32 rows x ALL j per block. -------
// grid (64, 8), 256 thr = 4 waves: rr = wv&1 (16-row group), js = wv>>1 (j-half
// of each stage). 8 stages x 8 j-words, LDS frag double-buffer, no partials.
__global__ __launch_bounds__(256) void attention7(
    const float* __restrict__ h, const unsigned short* __restrict__ hT2,
    const float* __restrict__ s1L, const float* __restrict__ s2L,
    const unsigned int* __restrict__ bitsT, float* __restrict__ out)
{
    __shared__ __align__(16) unsigned short frag[2][8][4][512];  // 64 KB ring
    __shared__ __align__(16) unsigned int mask_lds[2][64][16];   // 8 KB
    __shared__ __align__(16) float s2l[2048];                    // 8 KB

    int t = threadIdx.x, wv = t >> 6, lane = t & 63;
    int am = lane & 15, ag = lane >> 4;
    int rr = wv & 1, js = wv >> 1;
    int bx = blockIdx.x, b = blockIdx.y;

    float s1r = s1L[b * Nn + bx * 32 + rr * 16 + am];

    const unsigned int* msrc = bitsT + (size_t)(bx * 2) * 1024;  // 8 KB contiguous
    const float* ssrc = s2L + b * Nn;                            // 8 KB contiguous
    const unsigned short* slab = hT2 + (size_t)b * 131072;       // 64w x 4fb x 512

    // ---- prologue staging: mask, s2, stage-0 frags ----
#pragma unroll
    for (int k = 0; k < 2; ++k) {
        int sl = wv * 2 + k;                                     // 1KB slices 0..7
        gll16(msrc + sl * 256 + lane * 4, &((unsigned int*)mask_lds)[sl * 256]);
        gll16(ssrc + sl * 256 + lane * 4, &s2l[sl * 256]);
    }
#pragma unroll
    for (int k = 0; k < 8; ++k) {
        int si = wv * 8 + k, w = si >> 2, fb = si & 3;
        gll16(slab + (size_t)(w * 4 + fb) * 512 + lane * 8, &frag[0][w][fb][0]);
    }
    asm volatile("s_waitcnt vmcnt(0)" ::: "memory");
    __builtin_amdgcn_s_barrier();

    f32x4 acc0 = {0,0,0,0}, acc1 = {0,0,0,0}, acc2 = {0,0,0,0}, acc3 = {0,0,0,0};
    f32x4 accz = {0,0,0,0};
    const short8 vone = {(short)0x3F80, (short)0x3F80, (short)0x3F80, (short)0x3F80,
                         (short)0x3F80, (short)0x3F80, (short)0x3F80, (short)0x3F80};

#pragma unroll
    for (int s = 0; s < 8; ++s) {
        if (s < 7) {                                  // prefetch stage s+1
#pragma unroll
            for (int k = 0; k < 8; ++k) {
                int si = wv * 8 + k, w = si >> 2, fb = si & 3;
                gll16(slab + (size_t)(((s + 1) * 8 + w) * 4 + fb) * 512 + lane * 8,
                      &frag[(s + 1) & 1][w][fb][0]);
            }
        }
#pragma unroll
        for (int wi = 0; wi < 4; ++wi) {
            int wl = js * 4 + wi;                     // word-in-stage 0..7
            int Wg = s * 8 + wl;                      // global word
            unsigned wd = mask_lds[rr][Wg][am];
            float4 sa = *(const float4*)&s2l[Wg * 32 + 8 * ag];
            float4 sb = *(const float4*)&s2l[Wg * 32 + 8 * ag + 4];
            float se[8] = {sa.x, sa.y, sa.z, sa.w, sb.x, sb.y, sb.z, sb.w};
            float p[8];
#pragma unroll
            for (int e = 0; e < 8; ++e) {
                float x = s1r + se[e];
                float lr = fmaxf(x, ALPHA * x);
                float ev = __builtin_amdgcn_exp2f(lr);
                p[e] = ((wd >> (8 * ag + e)) & 1u) ? ev : 0.f;
            }
            int4v aw;
            aw.x = __builtin_amdgcn_perm(__builtin_bit_cast(unsigned, p[1]),
                                         __builtin_bit_cast(unsigned, p[0]), 0x07060302u);
            aw.y = __builtin_amdgcn_perm(__builtin_bit_cast(unsigned, p[3]),
                                         __builtin_bit_cast(unsigned, p[2]), 0x07060302u);
            aw.z = __builtin_amdgcn_perm(__builtin_bit_cast(unsigned, p[5]),
                                         __builtin_bit_cast(unsigned, p[4]), 0x07060302u);
            aw.w = __builtin_amdgcn_perm(__builtin_bit_cast(unsigned, p[7]),
                                         __builtin_bit_cast(unsigned, p[6]), 0x07060302u);
            short8 af = __builtin_bit_cast(short8, aw);
            short8 f0 = *(const short8*)&frag[s & 1][wl][0][lane * 8];
            short8 f1 = *(const short8*)&frag[s & 1][wl][1][lane * 8];
            short8 f2 = *(const short8*)&frag[s & 1][wl][2][lane * 8];
            short8 f3 = *(const short8*)&frag[s & 1][wl][3][lane * 8];
            acc0 = __builtin_amdgcn_mfma_f32_16x16x32_bf16(af, f0, acc0, 0, 0, 0);
            acc1 = __builtin_amdgcn_mfma_f32_16x16x32_bf16(af, f1, acc1, 0, 0, 0);
            acc2 = __builtin_amdgcn_mfma_f32_16x16x32_bf16(af, f2, acc2, 0, 0, 0);
            acc3 = __builtin_amdgcn_mfma_f32_16x16x32_bf16(af, f3, acc3, 0, 0, 0);
            accz = __builtin_amdgcn_mfma_f32_16x16x32_bf16(af, vone, accz, 0, 0, 0);
        }
        asm volatile("s_waitcnt vmcnt(0)" ::: "memory");
        __builtin_amdgcn_s_barrier();
    }

    // ---- epilogue: combine j-halves in LDS, normalize, residual, elu ----
    float* ep  = (float*)&frag[0][0][0][0];          // 16 KB (frag[0] is dead)
    float* zep = (float*)&mask_lds[0][0][0];         // 64 floats (stage-0 words)
#pragma unroll
    for (int q = 0; q < 4; ++q) {
        int rloc = rr * 16 + 4 * ag + q;
        ep[(js * 32 + rloc) * 64 +  0 + am] = acc0[q];
        ep[(js * 32 + rloc) * 64 + 16 + am] = acc1[q];
        ep[(js * 32 + rloc) * 64 + 32 + am] = acc2[q];
        ep[(js * 32 + rloc) * 64 + 48 + am] = acc3[q];
        if (am == 0) zep[js * 32 + rloc] = accz[q];
    }
    __syncthreads();

    int rl = t >> 3, fo = (t & 7) * 8;               // 32 rows x 8 f-octets
    float zinv = 1.f / (zep[rl] + zep[32 + rl]);
    size_t base = ((size_t)(b * Nn + bx * 32 + rl)) * 64 + fo;
    const float* e0p = &ep[rl * 64 + fo];
    const float* e1p = &ep[(32 + rl) * 64 + fo];
    float4 h0 = *(const float4*)&h[base];
    float4 h1 = *(const float4*)&h[base + 4];
    float4 o0, o1;
    o0.x = (e0p[0] + e1p[0]) * zinv + h0.x; o0.x = o0.x > 0.f ? o0.x : expm1f(o0.x);
    o0.y = (e0p[1] + e1p[1]) * zinv + h0.y; o0.y = o0.y > 0.f ? o0.y : expm1f(o0.y);
    o0.z = (e0p[2] + e1p[2]) * zinv + h0.z; o0.z = o0.z > 0.f ? o0.z : expm1f(o0.z);
    o0.w = (e0p[3] + e1p[3]) * zinv + h0.w; o0.w = o0.w > 0.f ? o0.w : expm1f(o0.w);
    o1.x = (e0p[4] + e1p[4]) * zinv + h1.x; o1.x = o1.x > 0.f ? o1.x : expm1f(o1.x);
    o1.y = (e0p[5] + e1p[5]) * zinv + h1.y; o1.y = o1.y > 0.f ? o1.y : expm1f(o1.y);
    o1.z = (e0p[6] + e1p[6]) * zinv + h1.z; o1.z = o1.z > 0.f ? o1.z : expm1f(o1.z);
    o1.w = (e0p[7] + e1p[7]) * zinv + h1.w; o1.w = o1.w > 0.f ? o1.w : expm1f(o1.w);
    *(float4*)&out[base] = o0;
    *(float4*)&out[base + 4] = o1;
}

// ---------------- launch ----------------
extern "C" void kernel_launch(void* const* d_in, const int* in_sizes, int n_in,
                              void* d_out, int out_size, void* d_ws, size_t ws_size,
                              hipStream_t stream) {
    const float* in  = (const float*)d_in[0];
    const int*   adj = (const int*)d_in[1];
    const float* W   = (const float*)d_in[2];
    const float* a   = (const float*)d_in[3];
    const float* nw  = (const float*)d_in[4];
    const float* nb  = (const float*)d_in[5];
    const float* gam = (const float*)d_in[6];
    const float* bet = (const float*)d_in[7];
    float* out = (float*)d_out;

    char* ws = (char*)d_ws;
    float* h   = (float*)ws;                                       // 4 MB
    float* s1L = (float*)(ws + (size_t)Bb * Nn * 64 * 4);          // 64 KB
    float* s2L = s1L + (size_t)Bb * Nn;                            // 64 KB
    unsigned int* bitsT = (unsigned int*)(s2L + (size_t)Bb * Nn);  // 512 KB
    unsigned short* hT2 = (unsigned short*)(bitsT + (size_t)Nn * Nn / 32); // 2 MB

    hipLaunchKernelGGL(pack_mask, dim3(Nn * Nn / 256), dim3(256), 0, stream, adj, bitsT);
    hipLaunchKernelGGL(node_transform, dim3(Bb * Nn / 4), dim3(256), 0, stream,
                       in, W, a, nw, nb, gam, bet, h, s1L, s2L, hT2);
    hipLaunchKernelGGL(attention7, dim3(Nn / 32, Bb), dim3(256), 0, stream,
                       h, hT2, s1L, s2L, bitsT, out);
}